// Round 8
// baseline (193.281 us; speedup 1.0000x reference)
//
#include <hip/hip_runtime.h>
#include <hip/hip_bf16.h>
#include <cstdint>

#define DIMD 1024
#define NH 16
#define DHD 64
#define BB 2
#define TT 2048
#define MROWS (BB * TT)   // 4096

typedef unsigned short u16;
typedef unsigned int u32;
typedef __attribute__((ext_vector_type(8))) __bf16 bf16x8;
typedef __attribute__((ext_vector_type(4))) float f32x4;

__device__ __forceinline__ u16 f2bf(float f) {
    union { float f; unsigned int i; } v; v.f = f;
    unsigned int u = v.i;
    unsigned int r = (u + 0x7fffu + ((u >> 16) & 1u)) >> 16;
    return (u16)r;
}
__device__ __forceinline__ int4 pack8(const float4& a, const float4& b) {
    union { int4 v; u16 u[8]; } t;
    t.u[0] = f2bf(a.x); t.u[1] = f2bf(a.y); t.u[2] = f2bf(a.z); t.u[3] = f2bf(a.w);
    t.u[4] = f2bf(b.x); t.u[5] = f2bf(b.y); t.u[6] = f2bf(b.z); t.u[7] = f2bf(b.w);
    return t.v;
}
// async global->LDS, 16B per lane. LDS dest = wave-uniform base + lane*16.
__device__ __forceinline__ void gl_lds16(const u16* g, u16* l) {
    __builtin_amdgcn_global_load_lds(
        (const __attribute__((address_space(1))) u32*)g,
        (__attribute__((address_space(3))) u32*)l, 16, 0, 0);
}

// ---------------------------------------------------------------------------
// One-shot f32 -> bf16 conversion of x, Wq|Wk|Wv (concat), Wo.
// ---------------------------------------------------------------------------
__global__ __launch_bounds__(256) void convert_all(const float* __restrict__ x,
                                                   const float* __restrict__ Wq,
                                                   const float* __restrict__ Wk,
                                                   const float* __restrict__ Wv,
                                                   const float* __restrict__ Wo,
                                                   u16* __restrict__ xb,
                                                   u16* __restrict__ wqkv,
                                                   u16* __restrict__ wob) {
    int t = blockIdx.x * 256 + threadIdx.x;
    const float* src; u16* dst; int rel;
    if (t < 524288)      { src = x;  dst = xb;             rel = t; }
    else if (t < 655360) { src = Wq; dst = wqkv;           rel = t - 524288; }
    else if (t < 786432) { src = Wk; dst = wqkv + 1048576; rel = t - 655360; }
    else if (t < 917504) { src = Wv; dst = wqkv + 2097152; rel = t - 786432; }
    else                 { src = Wo; dst = wob;            rel = t - 917504; }
    size_t e = (size_t)rel * 8;
    float4 a = *(const float4*)(src + e);
    float4 b = *(const float4*)(src + e + 4);
    *(int4*)(dst + e) = pack8(a, b);
}

// ---------------------------------------------------------------------------
// Fused QKV projection + RoPE + V-transpose epilogue.
// C[m,n] = sum_k xb[m,k]*wqkv[n,k], N=3072. 128x128 tile, BK=32.
// XCD-aware swizzle (1D grid, 768 blocks): xcd = bid&7 owns n-tiles
// {xcd, 8+xcd, 16+xcd} only -> 3 B-tiles (768 KB) stay L2-resident per XCD;
// A-tile reused 3x back-to-back (p fastest).
// ---------------------------------------------------------------------------
__global__ __launch_bounds__(256) void gemm_qkv(const u16* __restrict__ xb,
                                                const u16* __restrict__ wqkv,
                                                u16* __restrict__ qb,
                                                u16* __restrict__ kb,
                                                u16* __restrict__ vbT,
                                                const float* __restrict__ rot) {
    constexpr int Kd = 1024;
    __shared__ u16 As[128 * 32];
    __shared__ u16 Bs[128 * 32];

    const int bid = blockIdx.x;             // [0, 768)
    const int xcd = bid & 7;
    const int kk  = bid >> 3;               // [0, 96)
    const int m0  = (kk / 3) * 128;         // 32 m-tiles
    const int n0  = ((kk % 3) * 8 + xcd) * 128;   // [0, 3072)

    const int tid  = threadIdx.x;
    const int lane = tid & 63;
    const int w    = tid >> 6;

    const u16* Ag = xb   + (size_t)(m0 + 32 * w + (lane >> 2)) * Kd + (lane & 3) * 8;
    const u16* Bg = wqkv + (size_t)(n0 + 32 * w + (lane >> 2)) * Kd + (lane & 3) * 8;
    u16* Al0 = &As[(32 * w) * 32];
    u16* Al1 = &As[(32 * w + 16) * 32];
    u16* Bl0 = &Bs[(32 * w) * 32];
    u16* Bl1 = &Bs[(32 * w + 16) * 32];

    const int r16  = lane & 15;
    const int quad = lane >> 4;
    const int q8   = quad * 8;
    const int wm   = (w >> 1) * 64;
    const int wn   = (w & 1) * 64;

    f32x4 acc[4][4];
#pragma unroll
    for (int i = 0; i < 4; i++)
#pragma unroll
        for (int j = 0; j < 4; j++) acc[i][j] = f32x4{0.f, 0.f, 0.f, 0.f};

#pragma unroll 1
    for (int k0 = 0; k0 < Kd; k0 += 32) {
        __syncthreads();
        gl_lds16(Ag + k0, Al0);
        gl_lds16(Ag + 16 * Kd + k0, Al1);
        gl_lds16(Bg + k0, Bl0);
        gl_lds16(Bg + 16 * Kd + k0, Bl1);
        __syncthreads();   // drains vmcnt(0): loads landed

        bf16x8 af[4], bfr[4];
#pragma unroll
        for (int i = 0; i < 4; i++)
            af[i] = *(const bf16x8*)&As[(wm + i * 16 + r16) * 32 + q8];
#pragma unroll
        for (int j = 0; j < 4; j++)
            bfr[j] = *(const bf16x8*)&Bs[(wn + j * 16 + r16) * 32 + q8];
#pragma unroll
        for (int mi = 0; mi < 4; mi++)
#pragma unroll
            for (int ni = 0; ni < 4; ni++)
                acc[mi][ni] = __builtin_amdgcn_mfma_f32_16x16x32_bf16(
                    af[mi], bfr[ni], acc[mi][ni], 0, 0, 0);
    }

    // epilogue. col = n0 + wn + ni*16 + r16.
    const int wsel = n0 >> 10;
    const int nloc = (n0 & 1023) + wn;      // [0,1024), head = col>>6

    if (wsel < 2) {
        // RoPE: within-head d = ni*16+r16 (ni<2); pair = acc[..][ni]/[ni+2]
        u16* C = (wsel == 0) ? qb : kb;
#pragma unroll
        for (int mi = 0; mi < 4; mi++)
#pragma unroll
            for (int r = 0; r < 4; r++) {
                int row = m0 + wm + mi * 16 + quad * 4 + r;   // = b*T + t
#pragma unroll
                for (int ni = 0; ni < 2; ni++) {
                    int d = ni * 16 + r16;
                    float s0, c0, s1, c1;
                    __sincosf(rot[row * DHD + d], &s0, &c0);
                    __sincosf(rot[row * DHD + d + 32], &s1, &c1);
                    float x0 = acc[mi][ni][r], x1 = acc[mi][ni + 2][r];
                    C[(size_t)row * DIMD + nloc + d]      = f2bf(x0 * c0 - x1 * s0);
                    C[(size_t)row * DIMD + nloc + d + 32] = f2bf(x1 * c1 + x0 * s1);
                }
            }
    } else {
        // V transposed: vbT[((b*NH+h)*DHD + d)*TT + t]
#pragma unroll
        for (int mi = 0; mi < 4; mi++)
#pragma unroll
            for (int ni = 0; ni < 4; ni++)
#pragma unroll
                for (int r = 0; r < 4; r++) {
                    int row = m0 + wm + mi * 16 + quad * 4 + r;
                    int b   = row >> 11;
                    int t   = row & (TT - 1);
                    int col = nloc + ni * 16 + r16;
                    int h   = col >> 6;
                    int d   = col & 63;
                    vbT[((size_t)(b * NH + h) * DHD + d) * TT + t] =
                        f2bf(acc[mi][ni][r]);
                }
    }
}

// ---------------------------------------------------------------------------
// Windowed causal attention: keys in [q-128, q]. Block = (b, h, 64 queries).
// Q fragments direct from global; K + V^T staged once (1 staging barrier);
// P in its own per-wave LDS region (1 ordering barrier). 2 barriers total.
// ---------------------------------------------------------------------------
__global__ __launch_bounds__(256) void attn_kernel(const u16* __restrict__ Q,
                                                   const u16* __restrict__ K,
                                                   const u16* __restrict__ vbT,
                                                   u16* __restrict__ O) {
    constexpr int LDK = 72;    // 64 + 8 pad
    constexpr int LDV = 200;   // 192 + 8 pad
    __shared__ u16 Ks[192 * LDK];      // 27.6 KB
    __shared__ u16 VTs[64 * LDV];      // 25.6 KB  [d][key]
    __shared__ u16 Ps[4 * 16 * LDV];   // 25.6 KB  per-wave P

    const int tid = threadIdx.x;
    const int L   = tid & 63;
    const int w   = tid >> 6;
    const int b   = blockIdx.z;
    const int h   = blockIdx.y;
    const int q0  = blockIdx.x * 64;
    const int kstart = q0 - 128;

    for (int i = tid; i < 1536; i += 256) {
        int kr = i >> 3, c = (i & 7) * 8;
        int kk = kstart + kr;
        int4 val = make_int4(0, 0, 0, 0);
        if (kk >= 0)
            val = *(const int4*)&K[(size_t)(b * TT + kk) * DIMD + h * DHD + c];
        *(int4*)&Ks[kr * LDK + c] = val;
    }
    // V^T: 64 d-rows x 192 keys; vectorized 16B loads+writes
    for (int i = tid; i < 1536; i += 256) {
        int d = i / 24;
        int c = (i % 24) * 8;
        int kk = kstart + c;
        int4 val = make_int4(0, 0, 0, 0);
        if (kk >= 0)
            val = *(const int4*)&vbT[((size_t)(b * NH + h) * DHD + d) * TT + kk];
        *(int4*)&VTs[d * LDV + c] = val;
    }

    const int r16  = L & 15;
    const int quad = L >> 4;
    const int q8   = quad * 8;

    // Q fragments direct from global (overlaps with staging above)
    const size_t qrow = (size_t)(b * TT + q0 + w * 16 + r16) * DIMD + h * DHD;
    bf16x8 aq0 = *(const bf16x8*)&Q[qrow + q8];
    bf16x8 aq1 = *(const bf16x8*)&Q[qrow + 32 + q8];

    __syncthreads();   // staging barrier

    float st[12][4];
    float rmax[4] = {-1e30f, -1e30f, -1e30f, -1e30f};
    const float SC = 0.125f;   // 1/sqrt(64)

#pragma unroll
    for (int kt = 0; kt < 12; kt++) {
        bf16x8 bk0 = *(const bf16x8*)&Ks[(kt * 16 + r16) * LDK + q8];
        bf16x8 bk1 = *(const bf16x8*)&Ks[(kt * 16 + r16) * LDK + 32 + q8];
        f32x4 s = f32x4{0.f, 0.f, 0.f, 0.f};
        s = __builtin_amdgcn_mfma_f32_16x16x32_bf16(aq0, bk0, s, 0, 0, 0);
        s = __builtin_amdgcn_mfma_f32_16x16x32_bf16(aq1, bk1, s, 0, 0, 0);
        int ka = kstart + kt * 16 + r16;
#pragma unroll
        for (int r = 0; r < 4; r++) {
            int qa = q0 + w * 16 + quad * 4 + r;
            float sv = s[r] * SC;
            bool ok = (ka >= 0) && (ka <= qa) && (ka >= qa - 128);
            sv = ok ? sv : -1e30f;
            st[kt][r] = sv;
            rmax[r] = fmaxf(rmax[r], sv);
        }
    }
#pragma unroll
    for (int off = 8; off >= 1; off >>= 1)
#pragma unroll
        for (int r = 0; r < 4; r++)
            rmax[r] = fmaxf(rmax[r], __shfl_xor(rmax[r], off, 64));

    u16* Pw = &Ps[w * 16 * LDV];
    float rsum[4] = {0.f, 0.f, 0.f, 0.f};
#pragma unroll
    for (int kt = 0; kt < 12; kt++)
#pragma unroll
        for (int r = 0; r < 4; r++) {
            float p = __expf(st[kt][r] - rmax[r]);
            rsum[r] += p;
            Pw[(quad * 4 + r) * LDV + kt * 16 + r16] = f2bf(p);
        }
#pragma unroll
    for (int off = 8; off >= 1; off >>= 1)
#pragma unroll
        for (int r = 0; r < 4; r++)
            rsum[r] += __shfl_xor(rsum[r], off, 64);
    float rinv[4];
#pragma unroll
    for (int r = 0; r < 4; r++) rinv[r] = 1.0f / rsum[r];

    __syncthreads();   // orders P writes before aliased reads (wave-private data)

    bf16x8 pa[6];
#pragma unroll
    for (int kc = 0; kc < 6; kc++)
        pa[kc] = *(const bf16x8*)&Pw[r16 * LDV + kc * 32 + q8];

#pragma unroll
    for (int nt = 0; nt < 4; nt++) {
        f32x4 acc = f32x4{0.f, 0.f, 0.f, 0.f};
#pragma unroll
        for (int kc = 0; kc < 6; kc++) {
            bf16x8 bv = *(const bf16x8*)&VTs[(nt * 16 + r16) * LDV + kc * 32 + q8];
            acc = __builtin_amdgcn_mfma_f32_16x16x32_bf16(pa[kc], bv, acc, 0, 0, 0);
        }
#pragma unroll
        for (int r = 0; r < 4; r++) {
            int qa = q0 + w * 16 + quad * 4 + r;
            O[(size_t)(b * TT + qa) * DIMD + h * DHD + nt * 16 + r16] =
                f2bf(acc[r] * rinv[r]);
        }
    }
}

// ---------------------------------------------------------------------------
// Output projection: C = A @ Wo^T, A bf16 4096x1024, Wo bf16, C f32.
// 64x128 tile, XCD swizzle: n-tile = bid&7 -> one 256 KB B-tile per XCD.
// Grid 512 (1D).
// ---------------------------------------------------------------------------
__global__ __launch_bounds__(256) void gemm_out(const u16* __restrict__ A,
                                                const u16* __restrict__ Wb,
                                                float* __restrict__ C) {
    constexpr int Kd = 1024, Nd = 1024;
    __shared__ u16 As[64 * 32];
    __shared__ u16 Bs[128 * 32];

    const int bid = blockIdx.x;          // [0, 512)
    const int n0  = (bid & 7) * 128;
    const int m0  = (bid >> 3) * 64;

    const int tid  = threadIdx.x;
    const int lane = tid & 63;
    const int w    = tid >> 6;

    const u16* Ag = A  + (size_t)(m0 + 16 * w + (lane >> 2)) * Kd + (lane & 3) * 8;
    const u16* Bg = Wb + (size_t)(n0 + 32 * w + (lane >> 2)) * Kd + (lane & 3) * 8;
    u16* Al  = &As[(16 * w) * 32];
    u16* Bl0 = &Bs[(32 * w) * 32];
    u16* Bl1 = &Bs[(32 * w + 16) * 32];

    const int r16  = lane & 15;
    const int quad = lane >> 4;
    const int q8   = quad * 8;
    const int cb   = (w >> 1) * 64 + (w & 1) * 16;

    f32x4 acc[4][2];
#pragma unroll
    for (int i = 0; i < 4; i++)
#pragma unroll
        for (int j = 0; j < 2; j++) acc[i][j] = f32x4{0.f, 0.f, 0.f, 0.f};

#pragma unroll 1
    for (int k0 = 0; k0 < Kd; k0 += 32) {
        __syncthreads();
        gl_lds16(Ag + k0, Al);
        gl_lds16(Bg + k0, Bl0);
        gl_lds16(Bg + 16 * Kd + k0, Bl1);
        __syncthreads();

        bf16x8 af[4], bfr[2];
#pragma unroll
        for (int i = 0; i < 4; i++)
            af[i] = *(const bf16x8*)&As[(i * 16 + r16) * 32 + q8];
#pragma unroll
        for (int j = 0; j < 2; j++)
            bfr[j] = *(const bf16x8*)&Bs[(cb + j * 32 + r16) * 32 + q8];
#pragma unroll
        for (int mi = 0; mi < 4; mi++)
#pragma unroll
            for (int ni = 0; ni < 2; ni++)
                acc[mi][ni] = __builtin_amdgcn_mfma_f32_16x16x32_bf16(
                    af[mi], bfr[ni], acc[mi][ni], 0, 0, 0);
    }

#pragma unroll
    for (int mi = 0; mi < 4; mi++)
#pragma unroll
        for (int j = 0; j < 2; j++)
#pragma unroll
            for (int r = 0; r < 4; r++) {
                int row = m0 + mi * 16 + quad * 4 + r;
                C[(size_t)row * Nd + n0 + cb + j * 32 + r16] = acc[mi][j][r];
            }
}

// ---------------------------------------------------------------------------
extern "C" void kernel_launch(void* const* d_in, const int* in_sizes, int n_in,
                              void* d_out, int out_size, void* d_ws, size_t ws_size,
                              hipStream_t stream) {
    const float* x   = (const float*)d_in[0];
    const float* rot = (const float*)d_in[2];
    const float* Wq  = (const float*)d_in[3];
    const float* Wk  = (const float*)d_in[4];
    const float* Wv  = (const float*)d_in[5];
    const float* Wo  = (const float*)d_in[6];
    float* out = (float*)d_out;

    u16* xb   = (u16*)d_ws;               // 4M u16
    u16* wqkv = xb + 4194304;             // 3M
    u16* wob  = wqkv + 3145728;           // 1M
    u16* qb   = wob + 1048576;            // 4M
    u16* kb   = qb + 4194304;             // 4M
    u16* vbT  = kb + 4194304;             // 4M  ([b][h][d][t])
    u16* ab   = vbT + 4194304;            // 4M  (total 48 MB)

    convert_all<<<4096, 256, 0, stream>>>(x, Wq, Wk, Wv, Wo, xb, wqkv, wob);
    gemm_qkv<<<768, 256, 0, stream>>>(xb, wqkv, qb, kb, vbT, rot);
    attn_kernel<<<dim3(TT / 64, NH, BB), 256, 0, stream>>>(qb, kb, vbT, ab);
    gemm_out<<<512, 256, 0, stream>>>(ab, wob, out);
}

// Round 9
// 170.018 us; speedup vs baseline: 1.1368x; 1.1368x over previous
//
#include <hip/hip_runtime.h>
#include <hip/hip_bf16.h>
#include <cstdint>

#define DIMD 1024
#define NH 16
#define DHD 64
#define BB 2
#define TT 2048
#define MROWS (BB * TT)   // 4096

typedef unsigned short u16;
typedef unsigned int u32;
typedef __attribute__((ext_vector_type(8))) __bf16 bf16x8;
typedef __attribute__((ext_vector_type(4))) float f32x4;

__device__ __forceinline__ u16 f2bf(float f) {
    union { float f; unsigned int i; } v; v.f = f;
    unsigned int u = v.i;
    unsigned int r = (u + 0x7fffu + ((u >> 16) & 1u)) >> 16;
    return (u16)r;
}
__device__ __forceinline__ int4 pack8(const float4& a, const float4& b) {
    union { int4 v; u16 u[8]; } t;
    t.u[0] = f2bf(a.x); t.u[1] = f2bf(a.y); t.u[2] = f2bf(a.z); t.u[3] = f2bf(a.w);
    t.u[4] = f2bf(b.x); t.u[5] = f2bf(b.y); t.u[6] = f2bf(b.z); t.u[7] = f2bf(b.w);
    return t.v;
}

// ---------------------------------------------------------------------------
// One-shot f32 -> bf16 conversion of x, Wq|Wk|Wv (concat), Wo.
// ---------------------------------------------------------------------------
__global__ __launch_bounds__(256) void convert_all(const float* __restrict__ x,
                                                   const float* __restrict__ Wq,
                                                   const float* __restrict__ Wk,
                                                   const float* __restrict__ Wv,
                                                   const float* __restrict__ Wo,
                                                   u16* __restrict__ xb,
                                                   u16* __restrict__ wqkv,
                                                   u16* __restrict__ wob) {
    int t = blockIdx.x * 256 + threadIdx.x;
    const float* src; u16* dst; int rel;
    if (t < 524288)      { src = x;  dst = xb;             rel = t; }
    else if (t < 655360) { src = Wq; dst = wqkv;           rel = t - 524288; }
    else if (t < 786432) { src = Wk; dst = wqkv + 1048576; rel = t - 655360; }
    else if (t < 917504) { src = Wv; dst = wqkv + 2097152; rel = t - 786432; }
    else                 { src = Wo; dst = wob;            rel = t - 917504; }
    size_t e = (size_t)rel * 8;
    float4 a = *(const float4*)(src + e);
    float4 b = *(const float4*)(src + e + 4);
    *(int4*)(dst + e) = pack8(a, b);
}

// ---------------------------------------------------------------------------
// Fused QKV projection + RoPE + V-transpose epilogue.
// C[m,n] = sum_k xb[m,k]*wqkv[n,k], N=3072. 128x128 tile, BK=32.
// Register-staged double-buffered pipeline: global->VGPR loads for tile k+1
// are issued BEFORE compute(k) and consumed by ds_write after compute —
// the full compute phase covers the load latency. One barrier per k-step.
// Grid (24,32) = 768 blocks.
// ---------------------------------------------------------------------------
__global__ __launch_bounds__(256) void gemm_qkv(const u16* __restrict__ xb,
                                                const u16* __restrict__ wqkv,
                                                u16* __restrict__ qb,
                                                u16* __restrict__ kb,
                                                u16* __restrict__ vbT,
                                                const float* __restrict__ rot) {
    constexpr int Kd = 1024;
    __shared__ u16 As[2][128 * 32];
    __shared__ u16 Bs[2][128 * 32];

    const int tid  = threadIdx.x;
    const int lane = tid & 63;
    const int w    = tid >> 6;
    const int m0   = blockIdx.y * 128;
    const int n0   = blockIdx.x * 128;      // [0, 3072)

    // staging map: wave w owns rows [32w, 32w+32); lane -> (row, 16B chunk)
    const u16* Ag = xb   + (size_t)(m0 + 32 * w + (lane >> 2)) * Kd + (lane & 3) * 8;
    const u16* Bg = wqkv + (size_t)(n0 + 32 * w + (lane >> 2)) * Kd + (lane & 3) * 8;
    const int soff0 = (32 * w + (lane >> 2)) * 32 + (lane & 3) * 8;
    const int soff1 = soff0 + 16 * 32;

    const int r16  = lane & 15;
    const int quad = lane >> 4;
    const int q8   = quad * 8;
    const int wm   = (w >> 1) * 64;
    const int wn   = (w & 1) * 64;

    f32x4 acc[4][4];
#pragma unroll
    for (int i = 0; i < 4; i++)
#pragma unroll
        for (int j = 0; j < 4; j++) acc[i][j] = f32x4{0.f, 0.f, 0.f, 0.f};

    int4 a0, a1, b0, b1;
    auto loadregs = [&](int k) {
        a0 = *(const int4*)(Ag + k);
        a1 = *(const int4*)(Ag + 16 * Kd + k);
        b0 = *(const int4*)(Bg + k);
        b1 = *(const int4*)(Bg + 16 * Kd + k);
    };
    auto writebuf = [&](int buf) {
        *(int4*)&As[buf][soff0] = a0;
        *(int4*)&As[buf][soff1] = a1;
        *(int4*)&Bs[buf][soff0] = b0;
        *(int4*)&Bs[buf][soff1] = b1;
    };
    auto compute = [&](int buf) {
        bf16x8 af[4], bfr[4];
#pragma unroll
        for (int i = 0; i < 4; i++)
            af[i] = *(const bf16x8*)&As[buf][(wm + i * 16 + r16) * 32 + q8];
#pragma unroll
        for (int j = 0; j < 4; j++)
            bfr[j] = *(const bf16x8*)&Bs[buf][(wn + j * 16 + r16) * 32 + q8];
#pragma unroll
        for (int mi = 0; mi < 4; mi++)
#pragma unroll
            for (int ni = 0; ni < 4; ni++)
                acc[mi][ni] = __builtin_amdgcn_mfma_f32_16x16x32_bf16(
                    af[mi], bfr[ni], acc[mi][ni], 0, 0, 0);
    };

    // prologue: tile 0 -> buf0
    loadregs(0);
    writebuf(0);
    __syncthreads();

#pragma unroll 1
    for (int k0 = 0; k0 < Kd; k0 += 64) {
        loadregs(k0 + 32);            // k0+32 < Kd always (Kd%64==0)
        compute(0);
        writebuf(1);                  // vmcnt drained here, after compute
        __syncthreads();
        if (k0 + 64 < Kd) loadregs(k0 + 64);
        compute(1);
        if (k0 + 64 < Kd) {
            writebuf(0);
            __syncthreads();
        }
    }

    // epilogue. col = n0 + wn + ni*16 + r16.
    const int wsel = n0 >> 10;
    const int nloc = (n0 & 1023) + wn;      // [0,1024), head = col>>6

    if (wsel < 2) {
        // RoPE: within-head d = ni*16+r16 (ni<2); pair = acc[..][ni]/[ni+2]
        u16* C = (wsel == 0) ? qb : kb;
#pragma unroll
        for (int mi = 0; mi < 4; mi++)
#pragma unroll
            for (int r = 0; r < 4; r++) {
                int row = m0 + wm + mi * 16 + quad * 4 + r;   // = b*T + t
#pragma unroll
                for (int ni = 0; ni < 2; ni++) {
                    int d = ni * 16 + r16;
                    float s0, c0, s1, c1;
                    __sincosf(rot[row * DHD + d], &s0, &c0);
                    __sincosf(rot[row * DHD + d + 32], &s1, &c1);
                    float x0 = acc[mi][ni][r], x1 = acc[mi][ni + 2][r];
                    C[(size_t)row * DIMD + nloc + d]      = f2bf(x0 * c0 - x1 * s0);
                    C[(size_t)row * DIMD + nloc + d + 32] = f2bf(x1 * c1 + x0 * s1);
                }
            }
    } else {
        // V transposed: vbT[((b*NH+h)*DHD + d)*TT + t]
#pragma unroll
        for (int mi = 0; mi < 4; mi++)
#pragma unroll
            for (int ni = 0; ni < 4; ni++)
#pragma unroll
                for (int r = 0; r < 4; r++) {
                    int row = m0 + wm + mi * 16 + quad * 4 + r;
                    int b   = row >> 11;
                    int t   = row & (TT - 1);
                    int col = nloc + ni * 16 + r16;
                    int h   = col >> 6;
                    int d   = col & 63;
                    vbT[((size_t)(b * NH + h) * DHD + d) * TT + t] =
                        f2bf(acc[mi][ni][r]);
                }
    }
}

// ---------------------------------------------------------------------------
// Windowed causal attention: keys in [q-128, q]. Block = (b, h, 64 queries).
// Q fragments direct from global; K + V^T staged once (1 staging barrier);
// P in its own per-wave LDS region (1 ordering barrier). 2 barriers total.
// ---------------------------------------------------------------------------
__global__ __launch_bounds__(256) void attn_kernel(const u16* __restrict__ Q,
                                                   const u16* __restrict__ K,
                                                   const u16* __restrict__ vbT,
                                                   u16* __restrict__ O) {
    constexpr int LDK = 72;    // 64 + 8 pad
    constexpr int LDV = 200;   // 192 + 8 pad
    __shared__ u16 Ks[192 * LDK];      // 27.6 KB
    __shared__ u16 VTs[64 * LDV];      // 25.6 KB  [d][key]
    __shared__ u16 Ps[4 * 16 * LDV];   // 25.6 KB  per-wave P

    const int tid = threadIdx.x;
    const int L   = tid & 63;
    const int w   = tid >> 6;
    const int b   = blockIdx.z;
    const int h   = blockIdx.y;
    const int q0  = blockIdx.x * 64;
    const int kstart = q0 - 128;

    for (int i = tid; i < 1536; i += 256) {
        int kr = i >> 3, c = (i & 7) * 8;
        int kk = kstart + kr;
        int4 val = make_int4(0, 0, 0, 0);
        if (kk >= 0)
            val = *(const int4*)&K[(size_t)(b * TT + kk) * DIMD + h * DHD + c];
        *(int4*)&Ks[kr * LDK + c] = val;
    }
    // V^T: 64 d-rows x 192 keys; vectorized 16B loads+writes
    for (int i = tid; i < 1536; i += 256) {
        int d = i / 24;
        int c = (i % 24) * 8;
        int kk = kstart + c;
        int4 val = make_int4(0, 0, 0, 0);
        if (kk >= 0)
            val = *(const int4*)&vbT[((size_t)(b * NH + h) * DHD + d) * TT + kk];
        *(int4*)&VTs[d * LDV + c] = val;
    }

    const int r16  = L & 15;
    const int quad = L >> 4;
    const int q8   = quad * 8;

    // Q fragments direct from global (overlaps with staging above)
    const size_t qrow = (size_t)(b * TT + q0 + w * 16 + r16) * DIMD + h * DHD;
    bf16x8 aq0 = *(const bf16x8*)&Q[qrow + q8];
    bf16x8 aq1 = *(const bf16x8*)&Q[qrow + 32 + q8];

    __syncthreads();   // staging barrier

    float st[12][4];
    float rmax[4] = {-1e30f, -1e30f, -1e30f, -1e30f};
    const float SC = 0.125f;   // 1/sqrt(64)

#pragma unroll
    for (int kt = 0; kt < 12; kt++) {
        bf16x8 bk0 = *(const bf16x8*)&Ks[(kt * 16 + r16) * LDK + q8];
        bf16x8 bk1 = *(const bf16x8*)&Ks[(kt * 16 + r16) * LDK + 32 + q8];
        f32x4 s = f32x4{0.f, 0.f, 0.f, 0.f};
        s = __builtin_amdgcn_mfma_f32_16x16x32_bf16(aq0, bk0, s, 0, 0, 0);
        s = __builtin_amdgcn_mfma_f32_16x16x32_bf16(aq1, bk1, s, 0, 0, 0);
        int ka = kstart + kt * 16 + r16;
#pragma unroll
        for (int r = 0; r < 4; r++) {
            int qa = q0 + w * 16 + quad * 4 + r;
            float sv = s[r] * SC;
            bool ok = (ka >= 0) && (ka <= qa) && (ka >= qa - 128);
            sv = ok ? sv : -1e30f;
            st[kt][r] = sv;
            rmax[r] = fmaxf(rmax[r], sv);
        }
    }
#pragma unroll
    for (int off = 8; off >= 1; off >>= 1)
#pragma unroll
        for (int r = 0; r < 4; r++)
            rmax[r] = fmaxf(rmax[r], __shfl_xor(rmax[r], off, 64));

    u16* Pw = &Ps[w * 16 * LDV];
    float rsum[4] = {0.f, 0.f, 0.f, 0.f};
#pragma unroll
    for (int kt = 0; kt < 12; kt++)
#pragma unroll
        for (int r = 0; r < 4; r++) {
            float p = __expf(st[kt][r] - rmax[r]);
            rsum[r] += p;
            Pw[(quad * 4 + r) * LDV + kt * 16 + r16] = f2bf(p);
        }
#pragma unroll
    for (int off = 8; off >= 1; off >>= 1)
#pragma unroll
        for (int r = 0; r < 4; r++)
            rsum[r] += __shfl_xor(rsum[r], off, 64);
    float rinv[4];
#pragma unroll
    for (int r = 0; r < 4; r++) rinv[r] = 1.0f / rsum[r];

    __syncthreads();   // orders P writes before aliased reads

    bf16x8 pa[6];
#pragma unroll
    for (int kc = 0; kc < 6; kc++)
        pa[kc] = *(const bf16x8*)&Pw[r16 * LDV + kc * 32 + q8];

#pragma unroll
    for (int nt = 0; nt < 4; nt++) {
        f32x4 acc = f32x4{0.f, 0.f, 0.f, 0.f};
#pragma unroll
        for (int kc = 0; kc < 6; kc++) {
            bf16x8 bv = *(const bf16x8*)&VTs[(nt * 16 + r16) * LDV + kc * 32 + q8];
            acc = __builtin_amdgcn_mfma_f32_16x16x32_bf16(pa[kc], bv, acc, 0, 0, 0);
        }
#pragma unroll
        for (int r = 0; r < 4; r++) {
            int qa = q0 + w * 16 + quad * 4 + r;
            O[(size_t)(b * TT + qa) * DIMD + h * DHD + nt * 16 + r16] =
                f2bf(acc[r] * rinv[r]);
        }
    }
}

// ---------------------------------------------------------------------------
// Output projection: C = A @ Wo^T, A bf16 4096x1024, Wo bf16, C f32.
// 64x128 tile, register-staged double-buffered pipeline. Grid (8,64).
// ---------------------------------------------------------------------------
__global__ __launch_bounds__(256) void gemm_out(const u16* __restrict__ A,
                                                const u16* __restrict__ Wb,
                                                float* __restrict__ C) {
    constexpr int Kd = 1024, Nd = 1024;
    __shared__ u16 As[2][64 * 32];
    __shared__ u16 Bs[2][128 * 32];

    const int tid  = threadIdx.x;
    const int lane = tid & 63;
    const int w    = tid >> 6;
    const int m0   = blockIdx.y * 64;
    const int n0   = blockIdx.x * 128;

    const u16* Ag = A  + (size_t)(m0 + 16 * w + (lane >> 2)) * Kd + (lane & 3) * 8;
    const u16* Bg = Wb + (size_t)(n0 + 32 * w + (lane >> 2)) * Kd + (lane & 3) * 8;
    const int aoff  = (16 * w + (lane >> 2)) * 32 + (lane & 3) * 8;
    const int boff0 = (32 * w + (lane >> 2)) * 32 + (lane & 3) * 8;
    const int boff1 = boff0 + 16 * 32;

    const int r16  = lane & 15;
    const int quad = lane >> 4;
    const int q8   = quad * 8;
    const int cb   = (w >> 1) * 64 + (w & 1) * 16;

    f32x4 acc[4][2];
#pragma unroll
    for (int i = 0; i < 4; i++)
#pragma unroll
        for (int j = 0; j < 2; j++) acc[i][j] = f32x4{0.f, 0.f, 0.f, 0.f};

    int4 a0, b0, b1;
    auto loadregs = [&](int k) {
        a0 = *(const int4*)(Ag + k);
        b0 = *(const int4*)(Bg + k);
        b1 = *(const int4*)(Bg + 16 * Kd + k);
    };
    auto writebuf = [&](int buf) {
        *(int4*)&As[buf][aoff]  = a0;
        *(int4*)&Bs[buf][boff0] = b0;
        *(int4*)&Bs[buf][boff1] = b1;
    };
    auto compute = [&](int buf) {
        bf16x8 af[4], bfr[2];
#pragma unroll
        for (int i = 0; i < 4; i++)
            af[i] = *(const bf16x8*)&As[buf][(i * 16 + r16) * 32 + q8];
#pragma unroll
        for (int j = 0; j < 2; j++)
            bfr[j] = *(const bf16x8*)&Bs[buf][(cb + j * 32 + r16) * 32 + q8];
#pragma unroll
        for (int mi = 0; mi < 4; mi++)
#pragma unroll
            for (int ni = 0; ni < 2; ni++)
                acc[mi][ni] = __builtin_amdgcn_mfma_f32_16x16x32_bf16(
                    af[mi], bfr[ni], acc[mi][ni], 0, 0, 0);
    };

    loadregs(0);
    writebuf(0);
    __syncthreads();

#pragma unroll 1
    for (int k0 = 0; k0 < Kd; k0 += 64) {
        loadregs(k0 + 32);
        compute(0);
        writebuf(1);
        __syncthreads();
        if (k0 + 64 < Kd) loadregs(k0 + 64);
        compute(1);
        if (k0 + 64 < Kd) {
            writebuf(0);
            __syncthreads();
        }
    }

#pragma unroll
    for (int mi = 0; mi < 4; mi++)
#pragma unroll
        for (int j = 0; j < 2; j++)
#pragma unroll
            for (int r = 0; r < 4; r++) {
                int row = m0 + mi * 16 + quad * 4 + r;
                C[(size_t)row * Nd + n0 + cb + j * 32 + r16] = acc[mi][j][r];
            }
}

// ---------------------------------------------------------------------------
extern "C" void kernel_launch(void* const* d_in, const int* in_sizes, int n_in,
                              void* d_out, int out_size, void* d_ws, size_t ws_size,
                              hipStream_t stream) {
    const float* x   = (const float*)d_in[0];
    const float* rot = (const float*)d_in[2];
    const float* Wq  = (const float*)d_in[3];
    const float* Wk  = (const float*)d_in[4];
    const float* Wv  = (const float*)d_in[5];
    const float* Wo  = (const float*)d_in[6];
    float* out = (float*)d_out;

    u16* xb   = (u16*)d_ws;               // 4M u16
    u16* wqkv = xb + 4194304;             // 3M
    u16* wob  = wqkv + 3145728;           // 1M
    u16* qb   = wob + 1048576;            // 4M
    u16* kb   = qb + 4194304;             // 4M
    u16* vbT  = kb + 4194304;             // 4M  ([b][h][d][t])
    u16* ab   = vbT + 4194304;            // 4M  (total 48 MB)

    convert_all<<<4096, 256, 0, stream>>>(x, Wq, Wk, Wv, Wo, xb, wqkv, wob);
    gemm_qkv<<<dim3(3 * DIMD / 128, MROWS / 128), 256, 0, stream>>>(
        xb, wqkv, qb, kb, vbT, rot);
    attn_kernel<<<dim3(TT / 64, NH, BB), 256, 0, stream>>>(qb, kb, vbT, ab);
    gemm_out<<<dim3(DIMD / 128, MROWS / 64), 256, 0, stream>>>(ab, wob, out);
}